// Round 11
// baseline (2342.026 us; speedup 1.0000x reference)
//
#include <hip/hip_runtime.h>
#include <math.h>

// LSTM persistent kernel, R11: HYBRID MFMA+VALU matvec. One block per batch
// (64 blocks), 512 threads = 8 waves.
//
// R10 post-mortem: a 512x128 matvec costs ~620 cy/SIMD on the MFMA pipe
// (32 mfma_16x16x32 @ ~19cy, 15/16 of columns wasted) -- almost exactly the
// VALU fdot2 floor (512 cy). The pipes are SEPARATE and co-schedule across
// waves (m114), so splitting the matvec between them halves the compute
// term: waves 0-3 do elements 0..63 via MFMA (64 MFMAs -> ~310 cy/SIMD
// pipe), waves 4-7 do elements 64..127 via fdot2 (R5 layout, ~256 cy/SIMD
// issue). Both tails are in-wave; ONE barrier/step; both codepaths
// individually verified (R5 + R10, both absmax 2.441e-4).
// The 64-VGPR weight array is SHARED between paths (A-frags for MFMA waves,
// fdot2 v2h pairs for VALU waves) so peak pressure ~110 regs, no spill.
constexpr int Hdim = 128;
constexpr int TMAX = 4096;

typedef _Float16 v8h __attribute__((ext_vector_type(8)));
typedef _Float16 v2h __attribute__((ext_vector_type(2)));
typedef float v4f __attribute__((ext_vector_type(4)));

template <int CTRL>
__device__ __forceinline__ float dppf(float v) {
  return __int_as_float(
      __builtin_amdgcn_update_dpp(0, __float_as_int(v), CTRL, 0xF, 0xF, true));
}

#if __has_builtin(__builtin_amdgcn_exp2f)
__device__ __forceinline__ float exp2_fast(float x) {
  return __builtin_amdgcn_exp2f(x);
}
#else
__device__ __forceinline__ float exp2_fast(float x) {
  return __expf(x * 0.6931471805599453f);
}
#endif

__device__ __forceinline__ float sel4(v4f d, int r) {
  const float s01 = (r & 1) ? d.y : d.x;
  const float s23 = (r & 1) ? d.w : d.z;
  return (r & 2) ? s23 : s01;
}

__device__ __forceinline__ v2h get2(v8h v, int i) {  // constant i, subreg
  return v2h{v[2 * i], v[2 * i + 1]};
}

__global__ __launch_bounds__(512) void lstm_hybrid(
    const float* __restrict__ data, const float* __restrict__ h0,
    const float* __restrict__ c0, const float* __restrict__ W_ih,
    const float* __restrict__ W_hh, const float* __restrict__ b_ih,
    const float* __restrict__ b_hh, const float* __restrict__ W_out,
    const float* __restrict__ b_out, float* __restrict__ out, int T) {
  __shared__ __align__(16) float xs[TMAX];
  __shared__ __align__(16) _Float16 hbuf[2][Hdim];

  const int b = blockIdx.x;
  const int tid = threadIdx.x;
  const int lane = tid & 63;
  const int wv = tid >> 6;
  const bool mf = (wv < 4);  // wave-uniform type split

  // MFMA-path indices (R10): wave wv owns all 4 gates of els 16wv..16wv+15.
  const int p = lane >> 4;
  const int m = lane & 15;
  const int r = m & 3;
  // VALU-path indices (R5): quad owns element, lane q = gate & k-chunk.
  const int q = lane & 3;

  const int el = mf ? (16 * wv + 4 * p + r) : (64 + 16 * (wv - 4) + (lane >> 2));

  // Stage input row (coalesced float4).
  {
    const float4* src = (const float4*)(data + (size_t)b * T);
    float4* dst = (float4*)xs;
    for (int i = tid; i < T / 4; i += 512) dst[i] = src[i];
  }

  constexpr float L2E = 1.44269504088896f;

  // Shared 64-VGPR weight storage, Mk(g) pre-folded:
  //  MFMA waves: A[g][c] = A-frag of tile (rows 128g+16wv.., k-chunk 32c),
  //              lane holds A[m][32c+8p+j].
  //  VALU waves: A[g][c] = W_hh[128g+el][32q+8c .. +8) (fdot2 source pairs).
  v8h A[4][4];
  if (mf) {
#pragma unroll
    for (int g = 0; g < 4; ++g) {
      const int row = 128 * g + 16 * wv + m;
      const float Mr = (g == 2) ? 2.0f * L2E : -L2E;
      const float* wr = W_hh + (size_t)row * Hdim + 8 * p;
#pragma unroll
      for (int c = 0; c < 4; ++c) {
        float4 v0 = ((const float4*)(wr + 32 * c))[0];
        float4 v1 = ((const float4*)(wr + 32 * c))[1];
        A[g][c] = v8h{(_Float16)(Mr * v0.x), (_Float16)(Mr * v0.y),
                      (_Float16)(Mr * v0.z), (_Float16)(Mr * v0.w),
                      (_Float16)(Mr * v1.x), (_Float16)(Mr * v1.y),
                      (_Float16)(Mr * v1.z), (_Float16)(Mr * v1.w)};
      }
    }
  } else {
#pragma unroll
    for (int g = 0; g < 4; ++g) {
      const int row = 128 * g + el;
      const float Mr = (g == 2) ? 2.0f * L2E : -L2E;
      const float* wr = W_hh + (size_t)row * Hdim + 32 * q;
#pragma unroll
      for (int c = 0; c < 4; ++c) {
        float4 v0 = ((const float4*)(wr + 8 * c))[0];
        float4 v1 = ((const float4*)(wr + 8 * c))[1];
        A[g][c] = v8h{(_Float16)(Mr * v0.x), (_Float16)(Mr * v0.y),
                      (_Float16)(Mr * v0.z), (_Float16)(Mr * v0.w),
                      (_Float16)(Mr * v1.x), (_Float16)(Mr * v1.y),
                      (_Float16)(Mr * v1.z), (_Float16)(Mr * v1.w)};
      }
    }
  }

  // Tail constants. MFMA waves: all 4 gates of el. VALU waves: own gate q.
  float wih[4], bs[4];
  float As = 1.0f, Bs = 0.0f;
  if (mf) {
#pragma unroll
    for (int g = 0; g < 4; ++g) {
      const float Mr = (g == 2) ? 2.0f * L2E : -L2E;
      const int row = 128 * g + el;
      wih[g] = Mr * W_ih[row];
      bs[g] = Mr * (b_ih[row] + b_hh[row]);
    }
  } else {
    const int row = 128 * q + el;
    const float MkL = (q == 2) ? 2.0f * L2E : -L2E;
    wih[0] = MkL * W_ih[row];
    bs[0] = MkL * (b_ih[row] + b_hh[row]);
    As = (q == 2) ? -2.0f : 1.0f;
    Bs = (q == 2) ? 1.0f : 0.0f;
  }
  const bool qb0 = (q & 1) != 0;
  const bool qb1 = (q & 2) != 0;

  float cst = c0[(size_t)b * Hdim + el];
  if (tid < 128) hbuf[0][tid] = (_Float16)h0[(size_t)b * Hdim + tid];
  __syncthreads();

#pragma unroll 2
  for (int t = 0; t < T; ++t) {
    const _Float16* hb = hbuf[t & 1];
    const float xt = xs[t];
    float hnew;

    if (mf) {
      // B-frags: broadcast reads h[32c+8p+j].
      v8h bq[4];
#pragma unroll
      for (int c = 0; c < 4; ++c) bq[c] = *(const v8h*)(hb + 32 * c + 8 * p);

      v4f d[4];
#pragma unroll
      for (int g = 0; g < 4; ++g) {
        v4f acc = {0.f, 0.f, 0.f, 0.f};
#pragma unroll
        for (int c = 0; c < 4; ++c)
          acc = __builtin_amdgcn_mfma_f32_16x16x32_f16(A[g][c], bq[c], acc,
                                                       0, 0, 0);
        d[g] = acc;
      }

      const float zi = sel4(d[0], r);
      const float zf = sel4(d[1], r);
      const float zg = sel4(d[2], r);
      const float zo = sel4(d[3], r);

      const float yi = __builtin_amdgcn_rcpf(
          1.0f + exp2_fast(fmaf(xt, wih[0], bs[0]) + zi));
      const float yf = __builtin_amdgcn_rcpf(
          1.0f + exp2_fast(fmaf(xt, wih[1], bs[1]) + zf));
      const float yg =
          fmaf(-2.0f,
               __builtin_amdgcn_rcpf(
                   1.0f + exp2_fast(fmaf(xt, wih[2], bs[2]) + zg)),
               1.0f);
      const float yo = __builtin_amdgcn_rcpf(
          1.0f + exp2_fast(fmaf(xt, wih[3], bs[3]) + zo));

      cst = fmaf(yf, cst, yi * yg);
      const float th = fmaf(
          -2.0f, __builtin_amdgcn_rcpf(1.0f + exp2_fast(cst * (2.0f * L2E))),
          1.0f);
      hnew = yo * th;
    } else {
      // fdot2 path: my k-chunk of h, halfs [32q, 32q+32).
      v8h hx[4];
#pragma unroll
      for (int c = 0; c < 4; ++c) hx[c] = *(const v8h*)(hb + 32 * q + 8 * c);

      float a0 = 0.f, a1 = 0.f, a2 = 0.f, a3 = 0.f;
#pragma unroll
      for (int c = 0; c < 4; ++c) {
#pragma unroll
        for (int jj = 0; jj < 4; ++jj) {
          const v2h hp2 = get2(hx[c], jj);
          a0 = __builtin_amdgcn_fdot2(get2(A[0][c], jj), hp2, a0, false);
          a1 = __builtin_amdgcn_fdot2(get2(A[1][c], jj), hp2, a1, false);
          a2 = __builtin_amdgcn_fdot2(get2(A[2][c], jj), hp2, a2, false);
          a3 = __builtin_amdgcn_fdot2(get2(A[3][c], jj), hp2, a3, false);
        }
      }

      // 2-stage DPP reduce-scatter: lane q ends with gate q's full sum.
      float x01 = qb0 ? a1 : a0;
      float y01 = qb0 ? a0 : a1;
      x01 += dppf<0xB1>(y01);
      float x23 = qb0 ? a3 : a2;
      float y23 = qb0 ? a2 : a3;
      x23 += dppf<0xB1>(y23);
      float z = qb1 ? x23 : x01;
      float zz = qb1 ? x01 : x23;
      z += dppf<0x4E>(zz);

      const float pre = fmaf(xt, wih[0], bs[0]) + z;
      const float y =
          fmaf(As, __builtin_amdgcn_rcpf(1.0f + exp2_fast(pre)), Bs);

      const float yi = dppf<0x00>(y);
      const float yf = dppf<0x55>(y);
      const float yg = dppf<0xAA>(y);
      const float yo = dppf<0xFF>(y);

      cst = fmaf(yf, cst, yi * yg);
      const float th = fmaf(
          -2.0f, __builtin_amdgcn_rcpf(1.0f + exp2_fast(cst * (2.0f * L2E))),
          1.0f);
      hnew = yo * th;
    }

    const bool writer = mf ? (m < 4) : (q == 0);
    if (writer) hbuf[(t + 1) & 1][el] = (_Float16)hnew;
    __syncthreads();
  }

  // Final linear: out[b] = h_T . W_out + b_out (wave 0).
  if (tid < 64) {
    const _Float16* hf = hbuf[T & 1];
    float sum =
        (float)hf[tid] * W_out[tid] + (float)hf[tid + 64] * W_out[tid + 64];
#pragma unroll
    for (int off = 32; off > 0; off >>= 1) sum += __shfl_down(sum, off, 64);
    if (tid == 0) out[b] = sum + b_out[0];
  }
}

extern "C" void kernel_launch(void* const* d_in, const int* in_sizes, int n_in,
                              void* d_out, int out_size, void* d_ws,
                              size_t ws_size, hipStream_t stream) {
  const float* data = (const float*)d_in[0];
  const float* h0 = (const float*)d_in[1];
  const float* c0 = (const float*)d_in[2];
  const float* W_ih = (const float*)d_in[3];
  const float* W_hh = (const float*)d_in[4];
  const float* b_ih = (const float*)d_in[5];
  const float* b_hh = (const float*)d_in[6];
  const float* W_out = (const float*)d_in[7];
  const float* b_out = (const float*)d_in[8];
  float* out = (float*)d_out;

  const int B = in_sizes[1] / Hdim;  // 64
  const int T = in_sizes[0] / B;     // 4096

  lstm_hybrid<<<B, 512, 0, stream>>>(data, h0, c0, W_ih, W_hh, b_ih, b_hh,
                                     W_out, b_out, out, T);
}

// Round 12
// 1684.289 us; speedup vs baseline: 1.3905x; 1.3905x over previous
//
#include <hip/hip_runtime.h>
#include <math.h>

// LSTM persistent kernel, R12: R10's MFMA structure + VALU-tax removal.
// One block per batch (64 blocks), 512 threads = 8 waves; wave wv owns all
// 4 gates of elements 16wv..16wv+15; in-wave tail; one barrier/step.
//
// R10/R11 post-mortem: R10's wall (1104 cy/step) was NOT MFMA-pipe-bound
// (47% active util) -- active VALUBusy was 53% (583 cy/step), dominated by
// hidden per-step accumulator traffic: 16 v_accvgpr_write zero-inits +
// 16 v_accvgpr_read per wave per step. R12 removes what it can:
//  1. bias-in-accumulator: persistent acc_init[g] (Mk-scaled b_ih+b_hh for
//     rows 4p+reg) seeds the MFMA chain -> no zero-init movs, no tail adds.
//  2. c-major MFMA order: 4 independent gate chains round-robin -> dependent
//     MFMAs 4 apart, latency hidden.
//  3. xt prefetched as float4 every 4 steps (no per-step ds_read_b32 stall).
constexpr int Hdim = 128;
constexpr int TMAX = 4096;

typedef _Float16 v8h __attribute__((ext_vector_type(8)));
typedef float v4f __attribute__((ext_vector_type(4)));

#if __has_builtin(__builtin_amdgcn_exp2f)
__device__ __forceinline__ float exp2_fast(float x) {
  return __builtin_amdgcn_exp2f(x);
}
#else
__device__ __forceinline__ float exp2_fast(float x) {
  return __expf(x * 0.6931471805599453f);
}
#endif

__device__ __forceinline__ float sel4(v4f d, int r) {
  const float s01 = (r & 1) ? d.y : d.x;
  const float s23 = (r & 1) ? d.w : d.z;
  return (r & 2) ? s23 : s01;
}

__global__ __launch_bounds__(512) void lstm_mfma(
    const float* __restrict__ data, const float* __restrict__ h0,
    const float* __restrict__ c0, const float* __restrict__ W_ih,
    const float* __restrict__ W_hh, const float* __restrict__ b_ih,
    const float* __restrict__ b_hh, const float* __restrict__ W_out,
    const float* __restrict__ b_out, float* __restrict__ out, int T) {
  __shared__ __align__(16) float xs[TMAX];
  __shared__ __align__(16) _Float16 hbuf[2][Hdim];

  const int b = blockIdx.x;
  const int tid = threadIdx.x;
  const int lane = tid & 63;
  const int wv = tid >> 6;  // wave 0..7 owns elements 16wv..16wv+15
  const int p = lane >> 4;  // 0..3
  const int m = lane & 15;  // row-in-tile / col id
  const int r = m & 3;      // which d-reg this lane's tail handles
  const int el = 16 * wv + 4 * p + r;  // my tail element (copies for m>=4)

  // Stage input row (coalesced float4).
  {
    const float4* src = (const float4*)(data + (size_t)b * T);
    float4* dst = (float4*)xs;
    for (int i = tid; i < T / 4; i += 512) dst[i] = src[i];
  }

  constexpr float L2E = 1.44269504088896f;

  // A-frags: gate g -> rows [128g+16wv, 128g+16wv+16), chunk c -> k in
  // [32c,32c+32). Lane holds A[m][32c+8p+j], j=0..7, pre-scaled by Mk(g).
  v8h a[4][4];
#pragma unroll
  for (int g = 0; g < 4; ++g) {
    const int row = 128 * g + 16 * wv + m;
    const float Mr = (g == 2) ? 2.0f * L2E : -L2E;
    const float* wr = W_hh + (size_t)row * Hdim + 8 * p;
#pragma unroll
    for (int c = 0; c < 4; ++c) {
      float4 v0 = ((const float4*)(wr + 32 * c))[0];
      float4 v1 = ((const float4*)(wr + 32 * c))[1];
      a[g][c] = v8h{(_Float16)(Mr * v0.x), (_Float16)(Mr * v0.y),
                    (_Float16)(Mr * v0.z), (_Float16)(Mr * v0.w),
                    (_Float16)(Mr * v1.x), (_Float16)(Mr * v1.y),
                    (_Float16)(Mr * v1.z), (_Float16)(Mr * v1.w)};
    }
  }

  // Persistent accumulator seeds: acc_init[g].reg = Mk(g)*(b_ih+b_hh) of
  // row 128g + 16wv + 4p + reg (valid for every col m -> all lanes).
  v4f acc_init[4];
#pragma unroll
  for (int g = 0; g < 4; ++g) {
    const float Mr = (g == 2) ? 2.0f * L2E : -L2E;
    const int row = 128 * g + 16 * wv + 4 * p;
    acc_init[g] = v4f{Mr * (b_ih[row + 0] + b_hh[row + 0]),
                      Mr * (b_ih[row + 1] + b_hh[row + 1]),
                      Mr * (b_ih[row + 2] + b_hh[row + 2]),
                      Mr * (b_ih[row + 3] + b_hh[row + 3])};
  }

  // Tail constants: Mk-scaled W_ih for my element, per gate.
  float wih[4];
#pragma unroll
  for (int g = 0; g < 4; ++g) {
    const float Mr = (g == 2) ? 2.0f * L2E : -L2E;
    wih[g] = Mr * W_ih[128 * g + el];
  }

  float cst = c0[(size_t)b * Hdim + el];
  if (tid < 128) hbuf[0][tid] = (_Float16)h0[(size_t)b * Hdim + tid];
  __syncthreads();

  for (int t0 = 0; t0 < T; t0 += 4) {
    const float4 xv = *(const float4*)&xs[t0];  // 4 steps of x, one read
    const float xts[4] = {xv.x, xv.y, xv.z, xv.w};
#pragma unroll
    for (int u = 0; u < 4; ++u) {
      const int t = t0 + u;
      // B-frags: h chunk c, lane reads h[32c+8p+j] (16-lane broadcast).
      const _Float16* hb = hbuf[t & 1];
      v8h bq[4];
#pragma unroll
      for (int c = 0; c < 4; ++c) bq[c] = *(const v8h*)(hb + 32 * c + 8 * p);
      const float xt = xts[u];

      // 4 independent gate chains, c-major (dependent MFMAs 4 apart),
      // seeded with the bias.
      v4f d0 = acc_init[0], d1 = acc_init[1], d2 = acc_init[2],
          d3 = acc_init[3];
#pragma unroll
      for (int c = 0; c < 4; ++c) {
        d0 = __builtin_amdgcn_mfma_f32_16x16x32_f16(a[0][c], bq[c], d0, 0, 0, 0);
        d1 = __builtin_amdgcn_mfma_f32_16x16x32_f16(a[1][c], bq[c], d1, 0, 0, 0);
        d2 = __builtin_amdgcn_mfma_f32_16x16x32_f16(a[2][c], bq[c], d2, 0, 0, 0);
        d3 = __builtin_amdgcn_mfma_f32_16x16x32_f16(a[3][c], bq[c], d3, 0, 0, 0);
      }

      // In-wave tail: my element's 4 gate preacts (bias already inside).
      const float zi = sel4(d0, r);
      const float zf = sel4(d1, r);
      const float zg = sel4(d2, r);
      const float zo = sel4(d3, r);

      const float yi =
          __builtin_amdgcn_rcpf(1.0f + exp2_fast(fmaf(xt, wih[0], zi)));
      const float yf =
          __builtin_amdgcn_rcpf(1.0f + exp2_fast(fmaf(xt, wih[1], zf)));
      const float yg = fmaf(
          -2.0f, __builtin_amdgcn_rcpf(1.0f + exp2_fast(fmaf(xt, wih[2], zg))),
          1.0f);
      const float yo =
          __builtin_amdgcn_rcpf(1.0f + exp2_fast(fmaf(xt, wih[3], zo)));

      cst = fmaf(yf, cst, yi * yg);
      const float th = fmaf(
          -2.0f, __builtin_amdgcn_rcpf(1.0f + exp2_fast(cst * (2.0f * L2E))),
          1.0f);
      const float h = yo * th;

      if (m < 4) hbuf[(t + 1) & 1][el] = (_Float16)h;
      __syncthreads();
    }
  }

  // Final linear: out[b] = h_T . W_out + b_out (wave 0).
  if (tid < 64) {
    const _Float16* hf = hbuf[T & 1];
    float sum =
        (float)hf[tid] * W_out[tid] + (float)hf[tid + 64] * W_out[tid + 64];
#pragma unroll
    for (int off = 32; off > 0; off >>= 1) sum += __shfl_down(sum, off, 64);
    if (tid == 0) out[b] = sum + b_out[0];
  }
}

extern "C" void kernel_launch(void* const* d_in, const int* in_sizes, int n_in,
                              void* d_out, int out_size, void* d_ws,
                              size_t ws_size, hipStream_t stream) {
  const float* data = (const float*)d_in[0];
  const float* h0 = (const float*)d_in[1];
  const float* c0 = (const float*)d_in[2];
  const float* W_ih = (const float*)d_in[3];
  const float* W_hh = (const float*)d_in[4];
  const float* b_ih = (const float*)d_in[5];
  const float* b_hh = (const float*)d_in[6];
  const float* W_out = (const float*)d_in[7];
  const float* b_out = (const float*)d_in[8];
  float* out = (float*)d_out;

  const int B = in_sizes[1] / Hdim;  // 64
  const int T = in_sizes[0] / B;     // 4096

  lstm_mfma<<<B, 512, 0, stream>>>(data, h0, c0, W_ih, W_hh, b_ih, b_hh,
                                   W_out, b_out, out, T);
}